// Round 3
// baseline (3918.488 us; speedup 1.0000x reference)
//
#include <hip/hip_runtime.h>

#define TT 512
#define BB 32
#define II 512
#define HH 1024
#define G3 3072
#define TBH (TT * BB * HH) /* 16777216 */

typedef __attribute__((ext_vector_type(8))) short short8;
typedef __attribute__((ext_vector_type(4))) float f32x4;

__device__ __forceinline__ float sigmoidf_(float x) {
    return 1.f / (1.f + __expf(-x));
}
__device__ __forceinline__ float tanh_fast(float x) {
    float e2 = __expf(2.f * x);
    return 1.f - 2.f / (e2 + 1.f);
}
/* round-to-nearest-even f32 -> bf16 (top 16 bits) */
__device__ __forceinline__ unsigned rne16(float x) {
    unsigned u = __float_as_uint(x);
    return (u + 0x7FFFu + ((u >> 16) & 1u)) >> 16;
}
/* split x = hi + lo (both bf16); |x - hi - lo| <= ~2^-18 |x| */
__device__ __forceinline__ void bsplit(float x, unsigned& hi, unsigned& lo) {
    unsigned h16 = rne16(x);
    float xh = __uint_as_float(h16 << 16);
    hi = h16;
    lo = rne16(x - xh); /* x - xh is exact */
}

/* ---- gi = A(M x 512) @ w_ih(512 x 3072) + b_ih ---- */
__global__ __launch_bounds__(256) void k_gi_gemm(const float* __restrict__ A,
                                                 const float* __restrict__ B,
                                                 const float* __restrict__ bias,
                                                 float* __restrict__ C, int M) {
    __shared__ float As[8][128];
    __shared__ float Bs[8][128];
    int tid = threadIdx.x;
    int m0 = blockIdx.x * 128;
    int n0 = blockIdx.y * 128;
    int tx = tid & 15, ty = tid >> 4;
    int rowA = tid >> 1, kA = (tid & 1) * 4;
    int kB = tid >> 5, cB = (tid & 31) * 4;
    float acc[8][8] = {};
    for (int k0 = 0; k0 < 512; k0 += 8) {
        int rg = m0 + rowA;
        if (rg > M - 1) rg = M - 1;
        float4 a4 = *(const float4*)(A + (size_t)rg * 512 + k0 + kA);
        float4 b4 = *(const float4*)(B + (size_t)(k0 + kB) * G3 + n0 + cB);
        __syncthreads();
        As[kA + 0][rowA] = a4.x;
        As[kA + 1][rowA] = a4.y;
        As[kA + 2][rowA] = a4.z;
        As[kA + 3][rowA] = a4.w;
        *(float4*)&Bs[kB][cB] = b4;
        __syncthreads();
#pragma unroll
        for (int kk = 0; kk < 8; ++kk) {
            float4 a0 = *(const float4*)&As[kk][ty * 8];
            float4 a1 = *(const float4*)&As[kk][ty * 8 + 4];
            float4 b0 = *(const float4*)&Bs[kk][tx * 8];
            float4 b1 = *(const float4*)&Bs[kk][tx * 8 + 4];
            float av[8] = {a0.x, a0.y, a0.z, a0.w, a1.x, a1.y, a1.z, a1.w};
            float bv[8] = {b0.x, b0.y, b0.z, b0.w, b1.x, b1.y, b1.z, b1.w};
#pragma unroll
            for (int i = 0; i < 8; ++i)
#pragma unroll
                for (int j = 0; j < 8; ++j) acc[i][j] += av[i] * bv[j];
        }
    }
    float4 bi0 = *(const float4*)(bias + n0 + tx * 8);
    float4 bi1 = *(const float4*)(bias + n0 + tx * 8 + 4);
    float bb[8] = {bi0.x, bi0.y, bi0.z, bi0.w, bi1.x, bi1.y, bi1.z, bi1.w};
#pragma unroll
    for (int i = 0; i < 8; ++i) {
        int row = m0 + ty * 8 + i;
        if (row < M) {
            float4 s0 = {acc[i][0] + bb[0], acc[i][1] + bb[1], acc[i][2] + bb[2], acc[i][3] + bb[3]};
            float4 s1 = {acc[i][4] + bb[4], acc[i][5] + bb[5], acc[i][6] + bb[6], acc[i][7] + bb[7]};
            *(float4*)(C + (size_t)row * G3 + n0 + tx * 8) = s0;
            *(float4*)(C + (size_t)row * G3 + n0 + tx * 8 + 4) = s1;
        }
    }
}

/* ---- persistent recurrent kernel, v4 ----
   grid 256 = 64 h-col-groups x 4 batch-octets; block 512 thr = 8 waves.

   Exchange redesign (v3 polled 32KB/block/retry on out[] -> L3 congestion):
   - producers bsplit h(t) ONCE and store packed bf16 hi/lo pair-planes to
     hstage (u32 = same bytes as f32), parity double-buffered over t.
   - ordering: stage stores (sc0sc1) -> s_waitcnt vmcnt(0) -> barrier ->
     one 4B flag per block (flags[oct][hg] = t+1). R0-proven drain order.
   - each consumer WAVE polls only the 8 flags covering its 128-col k-slice
     (one broadcast 32B line/retry: poll traffic ~50x down), then loads its
     MFMA A-frags DIRECTLY global->reg: 16 pipelined u64 relaxed-agent
     loads, coalesced via [plane][batch][pair] layout. No LDS A-array, no
     stage barrier, no swizzle, no consumer bsplit, no NaN sentinels.
   - hprev carried in-register by the gate thread that produced it (exact
     f32; reloaded from out[] at chunk starts). out[] writes are plain.
   WAR on hstage parity: a block writes parity t&1 at step t only after its
   barrier-1, i.e. after ALL 64 octet flags >= t, i.e. after every block
   finished reading h(t-2) (same parity). Flags are global-step-monotonic;
   hstage persists across chunk dispatches, so chunk boundaries need no
   special case. */
__global__ __launch_bounds__(512, 2) void k_persist(const float* __restrict__ w_hh,
                                                    const float* __restrict__ gi,
                                                    const float* __restrict__ pad,
                                                    const float* __restrict__ b_hh,
                                                    float* __restrict__ out,
                                                    unsigned* __restrict__ flags,
                                                    unsigned* __restrict__ hstage,
                                                    int t0, int ct) {
    __shared__ float part[8 * 576]; /* [wave][g*192 + col*12 + b] */

    int tid = threadIdx.x;
    int hg = blockIdx.x & 63, boct = blockIdx.x >> 6;
    int hc0 = hg << 4;
    int b0 = boct << 3;

    int wk = tid >> 6;  /* wave id = k-slice [wk*128, wk*128+128) */
    int lane = tid & 63;
    int kg = lane >> 4; /* k-group within frag */
    int cx = lane & 15; /* A-row (batch) / C-col */

    /* ---- one-time: weights -> bf16 hi/lo frags in VGPRs (96 regs) ---- */
    short8 Bh[3][4], Bl[3][4];
#pragma unroll
    for (int g = 0; g < 3; ++g)
#pragma unroll
        for (int kf = 0; kf < 4; ++kf) {
            unsigned hh_[8], ll_[8];
#pragma unroll
            for (int j = 0; j < 8; ++j) {
                int k = wk * 128 + kf * 32 + kg * 8 + j;
                float w = w_hh[(size_t)k * G3 + hc0 + cx + g * HH];
                bsplit(w, hh_[j], ll_[j]);
            }
            union { unsigned u[4]; short8 s; } ph, pl;
#pragma unroll
            for (int r = 0; r < 4; ++r) {
                ph.u[r] = hh_[2 * r] | (hh_[2 * r + 1] << 16);
                pl.u[r] = ll_[2 * r] | (ll_[2 * r + 1] << 16);
            }
            Bh[g][kf] = ph.s;
            Bl[g][kf] = pl.s;
        }

    /* gate-thread constants (tid<128: col = hc0+cg, batch = b2) */
    int cg = tid & 15, b2 = tid >> 4;
    int col = hc0 + cg;
    int bg = b0 + b2;
    float bhr = 0.f, bhz = 0.f, bhn = 0.f, hprev = 0.f;
    if (tid < 128) {
        bhr = b_hh[col];
        bhz = b_hh[col + HH];
        bhn = b_hh[col + 2 * HH];
        if (t0 > 0) /* chunk resume: previous dispatch's h, fully visible */
            hprev = out[(size_t)(t0 - 1) * (BB * HH) + (size_t)bg * HH + col];
    }

    unsigned* oflags = flags + (boct << 6);
    unsigned* obase = hstage + boct * 16384; /* [par2][plane2][b8][pair512] u32 */

    for (int s = 0; s < ct; ++s) {
        int t = t0 + s;

        /* prefetch gi + pad (plain loads, consumed in gates phase) */
        float gir = 0.f, giz = 0.f, gin = 0.f, pv = 0.f;
        if (tid < 128) {
            const float* gp = gi + ((size_t)s * BB + bg) * G3 + col;
            gir = gp[0];
            giz = gp[HH];
            gin = gp[2 * HH];
            pv = pad[t * BB + bg];
        }

        /* ---- stage A-frags for my k-slice directly into registers ---- */
        short8 ah[4], al[4];
        bool have = (t > 0);
        if (have) {
            /* wave-slice readiness: 8 producer flags, one broadcast line */
            const unsigned* fp = oflags + (wk << 3) + (lane & 7);
            unsigned tgt = (unsigned)t;
            for (;;) {
                unsigned f = __hip_atomic_load(fp, __ATOMIC_RELAXED,
                                               __HIP_MEMORY_SCOPE_AGENT);
                if (__all(f >= tgt)) break;
            }
            asm volatile("" ::: "memory"); /* loads stay after the poll */
        }
        if (have && cx < 8) {
            int par = (t - 1) & 1;
            const unsigned long long* hq =
                (const unsigned long long*)(obase + ((par * 2 + 0) * 8 + cx) * 512);
            const unsigned long long* lq =
                (const unsigned long long*)(obase + ((par * 2 + 1) * 8 + cx) * 512);
#pragma unroll
            for (int kf = 0; kf < 4; ++kf) {
                int q0 = wk * 32 + kf * 8 + kg * 2; /* u64 index of pair p0 */
                union { unsigned long long q[2]; short8 s8; } uh, ul;
                uh.q[0] = __hip_atomic_load(hq + q0, __ATOMIC_RELAXED,
                                            __HIP_MEMORY_SCOPE_AGENT);
                uh.q[1] = __hip_atomic_load(hq + q0 + 1, __ATOMIC_RELAXED,
                                            __HIP_MEMORY_SCOPE_AGENT);
                ul.q[0] = __hip_atomic_load(lq + q0, __ATOMIC_RELAXED,
                                            __HIP_MEMORY_SCOPE_AGENT);
                ul.q[1] = __hip_atomic_load(lq + q0 + 1, __ATOMIC_RELAXED,
                                            __HIP_MEMORY_SCOPE_AGENT);
                ah[kf] = uh.s8;
                al[kf] = ul.s8;
            }
        } else {
            union { unsigned long long q[2]; short8 s8; } z;
            z.q[0] = 0ull;
            z.q[1] = 0ull;
#pragma unroll
            for (int kf = 0; kf < 4; ++kf) {
                ah[kf] = z.s8;
                al[kf] = z.s8;
            }
        }

        /* MFMA: 4 k-frags x 3 gates x 3 (bf16x3) = 36 per wave */
        f32x4 acc[3];
        acc[0] = (f32x4){0.f, 0.f, 0.f, 0.f};
        acc[1] = (f32x4){0.f, 0.f, 0.f, 0.f};
        acc[2] = (f32x4){0.f, 0.f, 0.f, 0.f};
#pragma unroll
        for (int kf = 0; kf < 4; ++kf)
#pragma unroll
            for (int g = 0; g < 3; ++g) {
                acc[g] = __builtin_amdgcn_mfma_f32_16x16x32_bf16(ah[kf], Bh[g][kf], acc[g], 0, 0, 0);
                acc[g] = __builtin_amdgcn_mfma_f32_16x16x32_bf16(ah[kf], Bl[g][kf], acc[g], 0, 0, 0);
                acc[g] = __builtin_amdgcn_mfma_f32_16x16x32_bf16(al[kf], Bh[g][kf], acc[g], 0, 0, 0);
            }
        /* partial C: lanes 0..31 hold valid batch rows 0..7 */
        if (lane < 32) {
            int r0 = (lane >> 4) * 4;
#pragma unroll
            for (int g = 0; g < 3; ++g)
                *(f32x4*)&part[wk * 576 + g * 192 + cx * 12 + r0] = acc[g];
        }
        __syncthreads();

        /* gates: 128 threads reduce 8 wave-partials per (g,b,col) */
        if (tid < 128) {
            float gh0 = 0.f, gh1 = 0.f, gh2 = 0.f;
#pragma unroll
            for (int w = 0; w < 8; ++w) {
                int base = w * 576 + cg * 12 + b2;
                gh0 += part[base];
                gh1 += part[base + 192];
                gh2 += part[base + 384];
            }
            float r = sigmoidf_(gir + gh0 + bhr);
            float z = sigmoidf_(giz + gh1 + bhz);
            float n = tanh_fast(gin + r * (gh2 + bhn));
            float hnew = (1.f - z) * n + z * hprev;
            hnew = pv * hprev + (1.f - pv) * hnew;
            hprev = hnew; /* exact f32 carried to next step */

            size_t oo = (size_t)t * (BB * HH) + (size_t)bg * HH + col;
            out[oo] = hnew;
            out[(size_t)TBH + oo] = hnew;

            /* producer-side split + pair-pack -> staging planes */
            unsigned hi_, lo_;
            bsplit(hnew, hi_, lo_);
            unsigned hi2 = __shfl_xor((int)hi_, 1);
            unsigned lo2 = __shfl_xor((int)lo_, 1);
            if (!(tid & 1)) {
                int par = t & 1;
                int pidx = col >> 1;
                __hip_atomic_store(obase + ((par * 2 + 0) * 8 + b2) * 512 + pidx,
                                   hi_ | (hi2 << 16), __ATOMIC_RELAXED,
                                   __HIP_MEMORY_SCOPE_AGENT);
                __hip_atomic_store(obase + ((par * 2 + 1) * 8 + b2) * 512 + pidx,
                                   lo_ | (lo2 << 16), __ATOMIC_RELAXED,
                                   __HIP_MEMORY_SCOPE_AGENT);
            }
        }
        /* drain stage stores to L3, then signal */
        asm volatile("s_waitcnt vmcnt(0)" ::: "memory");
        __syncthreads();
        if (tid == 0)
            __hip_atomic_store(&oflags[hg], (unsigned)(t + 1), __ATOMIC_RELAXED,
                               __HIP_MEMORY_SCOPE_AGENT);
    }
}

/* ---- emergency fallback if workspace is tiny: fused, slow, correct ---- */
__global__ __launch_bounds__(256) void k_step_slow(const float* __restrict__ x_t,
                                                   const float* __restrict__ pad_t,
                                                   const float* __restrict__ w_ih,
                                                   const float* __restrict__ w_hh,
                                                   const float* __restrict__ b_ih,
                                                   const float* __restrict__ b_hh,
                                                   const float* __restrict__ h_in,
                                                   float* __restrict__ h_out,
                                                   float* __restrict__ out, int t) {
    int g = blockIdx.x * 256 + threadIdx.x;
    int b = g >> 10, j = g & 1023;
    float gir = b_ih[j], giz = b_ih[j + HH], gin = b_ih[j + 2 * HH];
    for (int k = 0; k < II; ++k) {
        float xv = x_t[b * II + k];
        const float* wr = w_ih + (size_t)k * G3;
        gir += xv * wr[j];
        giz += xv * wr[j + HH];
        gin += xv * wr[j + 2 * HH];
    }
    float ghr = b_hh[j], ghz = b_hh[j + HH], ghn = b_hh[j + 2 * HH];
    for (int k = 0; k < HH; ++k) {
        float hv = h_in[b * HH + k];
        const float* wr = w_hh + (size_t)k * G3;
        ghr += hv * wr[j];
        ghz += hv * wr[j + HH];
        ghn += hv * wr[j + 2 * HH];
    }
    float hprev = h_in[b * HH + j];
    float p = pad_t[b];
    float r = sigmoidf_(gir + ghr);
    float z = sigmoidf_(giz + ghz);
    float n = tanh_fast(gin + r * ghn);
    float hnew = (1.f - z) * n + z * hprev;
    hnew = p * hprev + (1.f - p) * hnew;
    size_t o = (size_t)b * HH + j;
    h_out[o] = hnew;
    size_t oo = (size_t)t * (BB * HH) + o;
    out[oo] = hnew;
    out[(size_t)TBH + oo] = hnew;
}

extern "C" void kernel_launch(void* const* d_in, const int* in_sizes, int n_in,
                              void* d_out, int out_size, void* d_ws, size_t ws_size,
                              hipStream_t stream) {
    const float* x    = (const float*)d_in[0];
    const float* pad  = (const float*)d_in[1];
    const float* w_ih = (const float*)d_in[2];
    const float* w_hh = (const float*)d_in[3];
    const float* b_ih = (const float*)d_in[4];
    const float* b_hh = (const float*)d_in[5];
    float* out = (float*)d_out;

    char* wsb = (char*)d_ws;
    float* hA = (float*)wsb;                      /* 128 KB (fallback only) */
    float* hB = (float*)(wsb + 131072);           /* 128 KB (fallback only) */
    unsigned* flags = (unsigned*)(wsb + 262144);  /* 1 KB: 4 octets x 64 */
    unsigned* hstage = (unsigned*)(wsb + 263168); /* 256 KB: 4 octets x 64KB */
    float* gi = (float*)(wsb + 525312);           /* Tc * 32 * 3072 * 4 B */

    long long cap = (long long)ws_size - 525312LL;
    int Tc = cap > 0 ? (int)(cap / 393216LL) : 0;
    if (Tc > TT) Tc = TT;

    if (Tc >= 1) {
        hipMemsetAsync(flags, 0, 1024, stream); /* step counters := 0 */
        for (int t0 = 0; t0 < TT; t0 += Tc) {
            int ctn = (TT - t0 < Tc) ? (TT - t0) : Tc;
            int M = ctn * BB;
            dim3 g((M + 127) / 128, 24);
            k_gi_gemm<<<g, 256, 0, stream>>>(x + (size_t)t0 * BB * II, w_ih, b_ih, gi, M);
            k_persist<<<256, 512, 0, stream>>>(w_hh, gi, pad, b_hh, out, flags, hstage, t0, ctn);
        }
    } else {
        hipMemsetAsync(hA, 0, 131072, stream); /* h(t=0) = 0 */
        for (int t = 0; t < TT; ++t) {
            const float* hin = (t & 1) ? hB : hA;
            float* hout = (t & 1) ? hA : hB;
            k_step_slow<<<128, 256, 0, stream>>>(x + (size_t)t * BB * II, pad + t * BB,
                                                 w_ih, w_hh, b_ih, b_hh, hin, hout, out, t);
        }
    }
}

// Round 4
// 2372.730 us; speedup vs baseline: 1.6515x; 1.6515x over previous
//
#include <hip/hip_runtime.h>

#define TT 512
#define BB 32
#define II 512
#define HH 1024
#define G3 3072
#define TBH (TT * BB * HH) /* 16777216 */

typedef __attribute__((ext_vector_type(8))) short short8;
typedef __attribute__((ext_vector_type(4))) float f32x4;

__device__ __forceinline__ float sigmoidf_(float x) {
    return 1.f / (1.f + __expf(-x));
}
__device__ __forceinline__ float tanh_fast(float x) {
    float e2 = __expf(2.f * x);
    return 1.f - 2.f / (e2 + 1.f);
}
/* round-to-nearest-even f32 -> bf16 (top 16 bits) */
__device__ __forceinline__ unsigned rne16(float x) {
    unsigned u = __float_as_uint(x);
    return (u + 0x7FFFu + ((u >> 16) & 1u)) >> 16;
}
/* split x = hi + lo (both bf16); |x - hi - lo| <= ~2^-18 |x|.
   For finite x, neither hi nor lo can be 0xFFFF (bf16 NaN) -> sentinel-safe. */
__device__ __forceinline__ void bsplit(float x, unsigned& hi, unsigned& lo) {
    unsigned h16 = rne16(x);
    float xh = __uint_as_float(h16 << 16);
    hi = h16;
    lo = rne16(x - xh); /* x - xh is exact */
}

/* ---- gi = A(M x 512) @ w_ih(512 x 3072) + b_ih ---- */
__global__ __launch_bounds__(256) void k_gi_gemm(const float* __restrict__ A,
                                                 const float* __restrict__ B,
                                                 const float* __restrict__ bias,
                                                 float* __restrict__ C, int M) {
    __shared__ float As[8][128];
    __shared__ float Bs[8][128];
    int tid = threadIdx.x;
    int m0 = blockIdx.x * 128;
    int n0 = blockIdx.y * 128;
    int tx = tid & 15, ty = tid >> 4;
    int rowA = tid >> 1, kA = (tid & 1) * 4;
    int kB = tid >> 5, cB = (tid & 31) * 4;
    float acc[8][8] = {};
    for (int k0 = 0; k0 < 512; k0 += 8) {
        int rg = m0 + rowA;
        if (rg > M - 1) rg = M - 1;
        float4 a4 = *(const float4*)(A + (size_t)rg * 512 + k0 + kA);
        float4 b4 = *(const float4*)(B + (size_t)(k0 + kB) * G3 + n0 + cB);
        __syncthreads();
        As[kA + 0][rowA] = a4.x;
        As[kA + 1][rowA] = a4.y;
        As[kA + 2][rowA] = a4.z;
        As[kA + 3][rowA] = a4.w;
        *(float4*)&Bs[kB][cB] = b4;
        __syncthreads();
#pragma unroll
        for (int kk = 0; kk < 8; ++kk) {
            float4 a0 = *(const float4*)&As[kk][ty * 8];
            float4 a1 = *(const float4*)&As[kk][ty * 8 + 4];
            float4 b0 = *(const float4*)&Bs[kk][tx * 8];
            float4 b1 = *(const float4*)&Bs[kk][tx * 8 + 4];
            float av[8] = {a0.x, a0.y, a0.z, a0.w, a1.x, a1.y, a1.z, a1.w};
            float bv[8] = {b0.x, b0.y, b0.z, b0.w, b1.x, b1.y, b1.z, b1.w};
#pragma unroll
            for (int i = 0; i < 8; ++i)
#pragma unroll
                for (int j = 0; j < 8; ++j) acc[i][j] += av[i] * bv[j];
        }
    }
    float4 bi0 = *(const float4*)(bias + n0 + tx * 8);
    float4 bi1 = *(const float4*)(bias + n0 + tx * 8 + 4);
    float bb[8] = {bi0.x, bi0.y, bi0.z, bi0.w, bi1.x, bi1.y, bi1.z, bi1.w};
#pragma unroll
    for (int i = 0; i < 8; ++i) {
        int row = m0 + ty * 8 + i;
        if (row < M) {
            float4 s0 = {acc[i][0] + bb[0], acc[i][1] + bb[1], acc[i][2] + bb[2], acc[i][3] + bb[3]};
            float4 s1 = {acc[i][4] + bb[4], acc[i][5] + bb[5], acc[i][6] + bb[6], acc[i][7] + bb[7]};
            *(float4*)(C + (size_t)row * G3 + n0 + tx * 8) = s0;
            *(float4*)(C + (size_t)row * G3 + n0 + tx * 8 + 4) = s1;
        }
    }
}

/* ---- persistent recurrent kernel, v5 ----
   grid 256 = 64 h-col-groups x 4 batch-octets; block 512 thr = 8 waves.

   v3's zero-fence data-is-flag chain + v4's frag-direct packed staging:
   - hstage (workspace, 64 MB) holds FULL-HISTORY packed bf16 hi/lo frag
     u64s: [oct4][t 512][wk 8][plane2][kf4][j2][kg*8+cx 32]. Each address
     written exactly ONCE per launch -> no parity WAR, no flags, no fences.
     Pre-memset 0xFF per launch; 0xFFFF bf16 is NaN = unreachable for both
     hi (|h|<1) and lo (rne16 of finite) -> data is its own ready flag.
   - producer (128 gate threads): 1 bsplit + 3 shfl_xor to pair-pack, then
     1 thread per 4 stores two u64s (relaxed agent, straight to L3).
     Staging stores issue BEFORE the out[] stores (critical path first).
   - consumer: 16 u64 relaxed agent loads land DIRECTLY in MFMA A-frag
     registers (each instr: 32 lanes x 8B contiguous = 256B segment);
     retry re-issues only sentinel-bad lines. No consumer bsplit, no LDS
     A-staging, no swizzle. 2 barriers/step (part WAR only).
   - hprev carried in-register (exact f32); chunk resume reloads from out
     (previous dispatch's implicit release/acquire makes it visible). */
__global__ __launch_bounds__(512, 2) void k_persist(const float* __restrict__ w_hh,
                                                    const float* __restrict__ gi,
                                                    const float* __restrict__ pad,
                                                    const float* __restrict__ b_hh,
                                                    float* __restrict__ out,
                                                    unsigned long long* __restrict__ hstage,
                                                    int t0, int ct) {
    __shared__ float part[8 * 576]; /* [wave][g*192 + col*12 + b] */

    int tid = threadIdx.x;
    int hg = blockIdx.x & 63, boct = blockIdx.x >> 6;
    int hc0 = hg << 4;
    int b0 = boct << 3;

    int wk = tid >> 6;  /* wave id = k-slice [wk*128, wk*128+128) */
    int lane = tid & 63;
    int kg = lane >> 4; /* k-group within frag */
    int cx = lane & 15; /* A-row (batch) / C-col */

    /* ---- one-time: weights -> bf16 hi/lo frags in VGPRs (96 regs) ---- */
    short8 Bh[3][4], Bl[3][4];
#pragma unroll
    for (int g = 0; g < 3; ++g)
#pragma unroll
        for (int kf = 0; kf < 4; ++kf) {
            unsigned hh_[8], ll_[8];
#pragma unroll
            for (int j = 0; j < 8; ++j) {
                int k = wk * 128 + kf * 32 + kg * 8 + j;
                float w = w_hh[(size_t)k * G3 + hc0 + cx + g * HH];
                bsplit(w, hh_[j], ll_[j]);
            }
            union { unsigned u[4]; short8 s; } ph, pl;
#pragma unroll
            for (int r = 0; r < 4; ++r) {
                ph.u[r] = hh_[2 * r] | (hh_[2 * r + 1] << 16);
                pl.u[r] = ll_[2 * r] | (ll_[2 * r + 1] << 16);
            }
            Bh[g][kf] = ph.s;
            Bl[g][kf] = pl.s;
        }

    /* gate-thread constants (tid<128: col = hc0+cg, batch = b2) */
    int cg = tid & 15, b2 = tid >> 4;
    int col = hc0 + cg;
    int bg = b0 + b2;
    float bhr = 0.f, bhz = 0.f, bhn = 0.f, hprev = 0.f;
    if (tid < 128) {
        bhr = b_hh[col];
        bhz = b_hh[col + HH];
        bhn = b_hh[col + 2 * HH];
        if (t0 > 0) /* chunk resume: prev dispatch's h, flushed+visible */
            hprev = out[(size_t)(t0 - 1) * (BB * HH) + (size_t)bg * HH + col];
    }

    /* producer staging address: col -> (kf,j,kg) slot in frag order */
    int co = ((hg & 7) << 4) | cg; /* k-offset within my wk-slice, 0..127 */
    size_t sbase_p = (size_t)boct * 2097152 + (size_t)(hg >> 3) * 512 +
                     (size_t)((co >> 5) * 64 + ((co >> 2) & 1) * 32 +
                              ((co >> 3) & 3) * 8 + b2);
    /* consumer base: lane (kg,cx<8) reads 16 u64s at +plane*256+kf*64+j*32 */
    size_t cbase = (size_t)boct * 2097152 + (size_t)wk * 512 + (size_t)(kg * 8 + cx);

    for (int s = 0; s < ct; ++s) {
        int t = t0 + s;

        /* prefetch gi + pad (plain loads, consumed in gates phase) */
        float gir = 0.f, giz = 0.f, gin = 0.f, pv = 0.f;
        if (tid < 128) {
            const float* gp = gi + ((size_t)s * BB + bg) * G3 + col;
            gir = gp[0];
            giz = gp[HH];
            gin = gp[2 * HH];
            pv = pad[t * BB + bg];
        }

        /* ---- A-frags: poll-load packed staging of h(t-1) ---- */
        unsigned long long v[16];
        if (t > 0 && cx < 8) {
            const unsigned long long* sp = hstage + cbase + (size_t)(t - 1) * 4096;
#pragma unroll
            for (int i = 0; i < 16; ++i)
                v[i] = __hip_atomic_load(sp + (i >> 3) * 256 + ((i >> 1) & 3) * 64 +
                                             (i & 1) * 32,
                                         __ATOMIC_RELAXED, __HIP_MEMORY_SCOPE_AGENT);
            for (;;) {
                int bad = 0;
#pragma unroll
                for (int i = 0; i < 16; ++i)
                    if ((unsigned)v[i] == 0xFFFFFFFFu ||
                        (unsigned)(v[i] >> 32) == 0xFFFFFFFFu)
                        bad |= 1 << i;
                if (!bad) break;
#pragma unroll
                for (int i = 0; i < 16; ++i)
                    if (bad & (1 << i))
                        v[i] = __hip_atomic_load(sp + (i >> 3) * 256 +
                                                     ((i >> 1) & 3) * 64 + (i & 1) * 32,
                                                 __ATOMIC_RELAXED,
                                                 __HIP_MEMORY_SCOPE_AGENT);
            }
        } else {
#pragma unroll
            for (int i = 0; i < 16; ++i) v[i] = 0ull;
        }

        /* MFMA: 4 k-frags x 3 gates x 3 (bf16x3) = 36 per wave */
        f32x4 acc[3];
        acc[0] = (f32x4){0.f, 0.f, 0.f, 0.f};
        acc[1] = (f32x4){0.f, 0.f, 0.f, 0.f};
        acc[2] = (f32x4){0.f, 0.f, 0.f, 0.f};
#pragma unroll
        for (int kf = 0; kf < 4; ++kf) {
            union { unsigned long long q[2]; short8 s8; } uh, ul;
            uh.q[0] = v[kf * 2];
            uh.q[1] = v[kf * 2 + 1];
            ul.q[0] = v[8 + kf * 2];
            ul.q[1] = v[8 + kf * 2 + 1];
#pragma unroll
            for (int g = 0; g < 3; ++g) {
                acc[g] = __builtin_amdgcn_mfma_f32_16x16x32_bf16(uh.s8, Bh[g][kf], acc[g], 0, 0, 0);
                acc[g] = __builtin_amdgcn_mfma_f32_16x16x32_bf16(uh.s8, Bl[g][kf], acc[g], 0, 0, 0);
                acc[g] = __builtin_amdgcn_mfma_f32_16x16x32_bf16(ul.s8, Bh[g][kf], acc[g], 0, 0, 0);
            }
        }
        /* partial C: lanes 0..31 hold valid batch rows 0..7 */
        if (lane < 32) {
            int r0 = (lane >> 4) * 4;
#pragma unroll
            for (int g = 0; g < 3; ++g)
                *(f32x4*)&part[wk * 576 + g * 192 + cx * 12 + r0] = acc[g];
        }
        __syncthreads();

        /* gates: 128 threads reduce 8 wave-partials per (g,b,col) */
        if (tid < 128) {
            float gh0 = 0.f, gh1 = 0.f, gh2 = 0.f;
#pragma unroll
            for (int w = 0; w < 8; ++w) {
                int base = w * 576 + cg * 12 + b2;
                gh0 += part[base];
                gh1 += part[base + 192];
                gh2 += part[base + 384];
            }
            float r = sigmoidf_(gir + gh0 + bhr);
            float z = sigmoidf_(giz + gh1 + bhz);
            float n = tanh_fast(gin + r * (gh2 + bhn));
            float hnew = (1.f - z) * n + z * hprev;
            hnew = pv * hprev + (1.f - pv) * hnew;
            hprev = hnew; /* exact f32 carried to next step */

            /* ---- stage FIRST: split, pair-pack via 4-lane shuffles ---- */
            unsigned hi_, lo_;
            bsplit(hnew, hi_, lo_);
            unsigned hiA = hi_ | (((unsigned)__shfl_xor((int)hi_, 1)) << 16);
            unsigned loA = lo_ | (((unsigned)__shfl_xor((int)lo_, 1)) << 16);
            unsigned hiB = (unsigned)__shfl_xor((int)hiA, 2);
            unsigned loB = (unsigned)__shfl_xor((int)loA, 2);
            if ((cg & 3) == 0) {
                unsigned long long hq =
                    (unsigned long long)hiA | ((unsigned long long)hiB << 32);
                unsigned long long lq =
                    (unsigned long long)loA | ((unsigned long long)loB << 32);
                unsigned long long* dst = hstage + sbase_p + (size_t)t * 4096;
                __hip_atomic_store(dst, hq, __ATOMIC_RELAXED,
                                   __HIP_MEMORY_SCOPE_AGENT);
                __hip_atomic_store(dst + 256, lq, __ATOMIC_RELAXED,
                                   __HIP_MEMORY_SCOPE_AGENT);
            }
            size_t oo = (size_t)t * (BB * HH) + (size_t)bg * HH + col;
            out[oo] = hnew;
            out[(size_t)TBH + oo] = hnew;
        }
        /* WAR guard: part consumed before next step rewrites it */
        __syncthreads();
    }
}

/* ---- emergency fallback if workspace is tiny: fused, slow, correct ---- */
__global__ __launch_bounds__(256) void k_step_slow(const float* __restrict__ x_t,
                                                   const float* __restrict__ pad_t,
                                                   const float* __restrict__ w_ih,
                                                   const float* __restrict__ w_hh,
                                                   const float* __restrict__ b_ih,
                                                   const float* __restrict__ b_hh,
                                                   const float* __restrict__ h_in,
                                                   float* __restrict__ h_out,
                                                   float* __restrict__ out, int t) {
    int g = blockIdx.x * 256 + threadIdx.x;
    int b = g >> 10, j = g & 1023;
    float gir = b_ih[j], giz = b_ih[j + HH], gin = b_ih[j + 2 * HH];
    for (int k = 0; k < II; ++k) {
        float xv = x_t[b * II + k];
        const float* wr = w_ih + (size_t)k * G3;
        gir += xv * wr[j];
        giz += xv * wr[j + HH];
        gin += xv * wr[j + 2 * HH];
    }
    float ghr = b_hh[j], ghz = b_hh[j + HH], ghn = b_hh[j + 2 * HH];
    for (int k = 0; k < HH; ++k) {
        float hv = h_in[b * HH + k];
        const float* wr = w_hh + (size_t)k * G3;
        ghr += hv * wr[j];
        ghz += hv * wr[j + HH];
        ghn += hv * wr[j + 2 * HH];
    }
    float hprev = h_in[b * HH + j];
    float p = pad_t[b];
    float r = sigmoidf_(gir + ghr);
    float z = sigmoidf_(giz + ghz);
    float n = tanh_fast(gin + r * ghn);
    float hnew = (1.f - z) * n + z * hprev;
    hnew = p * hprev + (1.f - p) * hnew;
    size_t o = (size_t)b * HH + j;
    h_out[o] = hnew;
    size_t oo = (size_t)t * (BB * HH) + o;
    out[oo] = hnew;
    out[(size_t)TBH + oo] = hnew;
}

extern "C" void kernel_launch(void* const* d_in, const int* in_sizes, int n_in,
                              void* d_out, int out_size, void* d_ws, size_t ws_size,
                              hipStream_t stream) {
    const float* x    = (const float*)d_in[0];
    const float* pad  = (const float*)d_in[1];
    const float* w_ih = (const float*)d_in[2];
    const float* w_hh = (const float*)d_in[3];
    const float* b_ih = (const float*)d_in[4];
    const float* b_hh = (const float*)d_in[5];
    float* out = (float*)d_out;

    char* wsb = (char*)d_ws;
    float* hA = (float*)wsb;            /* 128 KB (fallback only) */
    float* hB = (float*)(wsb + 131072); /* 128 KB (fallback only) */
    unsigned long long* hstage = (unsigned long long*)(wsb + 262144); /* 64 MB */
    float* gi = (float*)(wsb + 262144 + 67108864); /* Tc * 32 * 3072 * 4 B */

    long long cap = (long long)ws_size - 262144LL - 67108864LL;
    int Tc = cap > 0 ? (int)(cap / 393216LL) : 0;
    if (Tc > TT) Tc = TT;

    if (Tc >= 1) {
        /* sentinel-fill staging: 0xFFFF bf16 = NaN, unreachable */
        hipMemsetAsync(hstage, 0xFF, 67108864, stream);
        for (int t0 = 0; t0 < TT; t0 += Tc) {
            int ctn = (TT - t0 < Tc) ? (TT - t0) : Tc;
            int M = ctn * BB;
            dim3 g((M + 127) / 128, 24);
            k_gi_gemm<<<g, 256, 0, stream>>>(x + (size_t)t0 * BB * II, w_ih, b_ih, gi, M);
            k_persist<<<256, 512, 0, stream>>>(w_hh, gi, pad, b_hh, out, hstage, t0, ctn);
        }
    } else {
        hipMemsetAsync(hA, 0, 131072, stream); /* h(t=0) = 0 */
        for (int t = 0; t < TT; ++t) {
            const float* hin = (t & 1) ? hB : hA;
            float* hout = (t & 1) ? hA : hB;
            k_step_slow<<<128, 256, 0, stream>>>(x + (size_t)t * BB * II, pad + t * BB,
                                                 w_ih, w_hh, b_ih, b_hh, hin, hout, out, t);
        }
    }
}